// Round 1
// baseline (3613.854 us; speedup 1.0000x reference)
//
#include <hip/hip_runtime.h>
#include <hip/hip_bf16.h>
#include <stdint.h>

typedef __attribute__((ext_vector_type(8))) __bf16 bf16x8;
typedef __attribute__((ext_vector_type(8))) unsigned short us8;
typedef __attribute__((ext_vector_type(4))) float f32x4;

#define BM 128
#define BN 128
#define BK 64

__device__ inline float bf2f(unsigned short u) {
  unsigned v = ((unsigned)u) << 16;
  float f;
  __builtin_memcpy(&f, &v, 4);
  return f;
}

__device__ inline unsigned short f2bf(float f) {
  unsigned u;
  __builtin_memcpy(&u, &f, 4);
  unsigned r = 0x7FFFu + ((u >> 16) & 1u);   // RNE
  u += r;
  return (unsigned short)(u >> 16);
}

__device__ inline void gload16(const void* g, void* l) {
  __builtin_amdgcn_global_load_lds(
      (const __attribute__((address_space(1))) unsigned int*)g,
      (__attribute__((address_space(3))) unsigned int*)l, 16, 0, 0);
}

// ---------------- fp32 -> bf16 convert ----------------
__global__ void cvt_kernel(const float* __restrict__ in,
                           unsigned short* __restrict__ out, int n4) {
  int i = blockIdx.x * blockDim.x + threadIdx.x;
  int stride = gridDim.x * blockDim.x;
  const float4* in4 = reinterpret_cast<const float4*>(in);
  ushort4* out4 = reinterpret_cast<ushort4*>(out);
  for (int idx = i; idx < n4; idx += stride) {
    float4 v = in4[idx];
    ushort4 o;
    o.x = f2bf(v.x); o.y = f2bf(v.y); o.z = f2bf(v.z); o.w = f2bf(v.w);
    out4[idx] = o;
  }
}

// ---------------- GEMM + per-tile (max, sumexp) ----------------
// grid: num_mb * num_vb blocks of 256 threads.
// A = xb (N x H bf16, row-major), B = wb (V x H bf16, row-major) -> C = A * B^T tile.
// Epilogue: per row of the 128x128 logits tile, write running (max, sumexp)
// to pm/ps at [vb * N + row].
__launch_bounds__(256, 2)
__global__ void gemm_lse_kernel(const unsigned short* __restrict__ xb,
                                const unsigned short* __restrict__ wb,
                                float* __restrict__ pm, float* __restrict__ ps,
                                int N, int H, int V) {
  __shared__ __align__(16) unsigned short Als[BM * BK];  // 16 KB
  __shared__ __align__(16) unsigned short Bls[BN * BK];  // 16 KB

  const int tid = threadIdx.x;
  const int l = tid & 63;
  const int w = tid >> 6;
  const int wr = w >> 1, wc = w & 1;

  // bijective XCD-aware swizzle (nwg divisible by 8: 64*250=16000)
  const int nwg = gridDim.x;
  const int chunk = nwg >> 3;
  const int id = blockIdx.x;
  const int sid = (id & 7) * chunk + (id >> 3);
  const int num_mb = N / BM;
  const int mb = sid % num_mb;
  const int vb = sid / num_mb;

  const int brow = mb * BM;
  const int bcol = vb * BN;

  f32x4 acc[4][4];
#pragma unroll
  for (int mi = 0; mi < 4; ++mi)
#pragma unroll
    for (int ni = 0; ni < 4; ++ni)
      acc[mi][ni] = (f32x4){0.f, 0.f, 0.f, 0.f};

  const int lrow = l >> 3;        // 0..7 within an 8-row chunk
  const int lcol = (l & 7) * 8;   // 0..56, 8 bf16 each

  for (int kt = 0; kt < H; kt += BK) {
#pragma unroll
    for (int t = 0; t < 4; ++t) {
      const int c = w * 4 + t;    // chunk 0..15, wave-uniform
      const unsigned short* src =
          xb + (size_t)(brow + c * 8 + lrow) * H + kt + lcol;
      gload16(src, &Als[c * 512]);
    }
#pragma unroll
    for (int t = 0; t < 4; ++t) {
      const int c = w * 4 + t;
      const unsigned short* src =
          wb + (size_t)(bcol + c * 8 + lrow) * H + kt + lcol;
      gload16(src, &Bls[c * 512]);
    }
    __syncthreads();   // drains vmcnt for global_load_lds

#pragma unroll
    for (int ks = 0; ks < 2; ++ks) {
      bf16x8 af[4], bfr[4];
#pragma unroll
      for (int mi = 0; mi < 4; ++mi)
        af[mi] = *reinterpret_cast<const bf16x8*>(
            &Als[(wr * 64 + mi * 16 + (l & 15)) * BK + ks * 32 + (l >> 4) * 8]);
#pragma unroll
      for (int ni = 0; ni < 4; ++ni)
        bfr[ni] = *reinterpret_cast<const bf16x8*>(
            &Bls[(wc * 64 + ni * 16 + (l & 15)) * BK + ks * 32 + (l >> 4) * 8]);
#pragma unroll
      for (int mi = 0; mi < 4; ++mi)
#pragma unroll
        for (int ni = 0; ni < 4; ++ni)
          acc[mi][ni] = __builtin_amdgcn_mfma_f32_16x16x32_bf16(
              af[mi], bfr[ni], acc[mi][ni], 0, 0, 0);
    }
    __syncthreads();
  }

  // ---- epilogue: per-row max & sumexp over this tile's 128 columns ----
  // C frag layout (16x16x32): col = lane&15, row = (lane>>4)*4 + reg.
  float mrow[4][4], srow[4][4];
#pragma unroll
  for (int mi = 0; mi < 4; ++mi) {
#pragma unroll
    for (int j = 0; j < 4; ++j) {
      float m = acc[mi][0][j];
#pragma unroll
      for (int ni = 1; ni < 4; ++ni) m = fmaxf(m, acc[mi][ni][j]);
#pragma unroll
      for (int off = 1; off < 16; off <<= 1)
        m = fmaxf(m, __shfl_xor(m, off, 64));
      float s = 0.f;
#pragma unroll
      for (int ni = 0; ni < 4; ++ni) s += __expf(acc[mi][ni][j] - m);
#pragma unroll
      for (int off = 1; off < 16; off <<= 1) s += __shfl_xor(s, off, 64);
      mrow[mi][j] = m;
      srow[mi][j] = s;
    }
  }

  float* red_m = (float*)(void*)Als;   // reuse LDS: [2][128]
  float* red_s = red_m + 256;
  if ((l & 15) == 0) {
    const int g = l >> 4;
#pragma unroll
    for (int mi = 0; mi < 4; ++mi)
#pragma unroll
      for (int j = 0; j < 4; ++j) {
        const int row = wr * 64 + mi * 16 + g * 4 + j;
        red_m[wc * 128 + row] = mrow[mi][j];
        red_s[wc * 128 + row] = srow[mi][j];
      }
  }
  __syncthreads();
  if (tid < 128) {
    const int row = tid;
    const float m0 = red_m[row], m1 = red_m[128 + row];
    const float s0 = red_s[row], s1 = red_s[128 + row];
    const float M = fmaxf(m0, m1);
    const float S = s0 * __expf(m0 - M) + s1 * __expf(m1 - M);
    const size_t o = (size_t)vb * N + brow + row;
    pm[o] = M;
    ps[o] = S;
  }
}

// ---------------- per-row LSE merge + target logit + loss accumulate ----------------
__global__ void reduce_kernel(const float* __restrict__ pm,
                              const float* __restrict__ ps,
                              const unsigned short* __restrict__ xb,
                              const unsigned short* __restrict__ wb,
                              const int* __restrict__ tgt,
                              float* __restrict__ accum,  // [0]=sum nll, [1]=count
                              int N, int H, int nvb) {
  const int l = threadIdx.x & 63;
  const int w = threadIdx.x >> 6;
  const int row = blockIdx.x * 4 + w;
  if (row >= N) return;

  float M = -INFINITY, S = 0.f;
  for (int vb = l; vb < nvb; vb += 64) {
    const float m = pm[(size_t)vb * N + row];
    const float s = ps[(size_t)vb * N + row];
    const float nM = fmaxf(M, m);
    S = S * __expf(M - nM) + s * __expf(m - nM);
    M = nM;
  }
#pragma unroll
  for (int off = 1; off < 64; off <<= 1) {
    const float om = __shfl_xor(M, off, 64);
    const float os = __shfl_xor(S, off, 64);
    const float nM = fmaxf(M, om);
    S = S * __expf(M - nM) + os * __expf(om - nM);
    M = nM;
  }

  const int t = tgt[row];
  const bool valid = (t != -100);
  float dot = 0.f;
  if (valid) {
    const unsigned short* xr = xb + (size_t)row * H;
    const unsigned short* wrow = wb + (size_t)t * H;
    for (int k = l * 8; k < H; k += 64 * 8) {
      const us8 xv = *reinterpret_cast<const us8*>(xr + k);
      const us8 wv = *reinterpret_cast<const us8*>(wrow + k);
#pragma unroll
      for (int j = 0; j < 8; ++j) dot += bf2f(xv[j]) * bf2f(wv[j]);
    }
#pragma unroll
    for (int off = 1; off < 64; off <<= 1) dot += __shfl_xor(dot, off, 64);
  }

  if (l == 0) {
    const float lse = M + __logf(S);
    const float nll = valid ? (lse - dot) : 0.f;
    atomicAdd(&accum[0], nll);
    if (valid) atomicAdd(&accum[1], 1.f);
  }
}

__global__ void finalize_kernel(const float* __restrict__ accum,
                                float* __restrict__ out) {
  out[0] = accum[0] / fmaxf(accum[1], 1.f);
}

extern "C" void kernel_launch(void* const* d_in, const int* in_sizes, int n_in,
                              void* d_out, int out_size, void* d_ws,
                              size_t ws_size, hipStream_t stream) {
  const float* x = (const float*)d_in[0];
  const float* wt = (const float*)d_in[1];
  const int* tgt = (const int*)d_in[2];
  float* out = (float*)d_out;

  const int N = in_sizes[2];            // 8192
  const int H = in_sizes[0] / N;        // 4096
  const int V = in_sizes[1] / H;        // 32000
  const int nvb = V / BN;               // 250
  const int nmb = N / BM;               // 64

  unsigned char* ws = (unsigned char*)d_ws;
  unsigned short* xb = (unsigned short*)ws;
  size_t off = (size_t)N * H * 2;
  unsigned short* wb = (unsigned short*)(ws + off);
  off += (size_t)V * H * 2;
  float* pm = (float*)(ws + off);
  off += (size_t)nvb * N * 4;
  float* ps = (float*)(ws + off);
  off += (size_t)nvb * N * 4;
  float* accum = (float*)(ws + off);

  hipMemsetAsync(accum, 0, 2 * sizeof(float), stream);

  cvt_kernel<<<2048, 256, 0, stream>>>(x, xb, (int)(((size_t)N * H) / 4));
  cvt_kernel<<<4096, 256, 0, stream>>>(wt, wb, (int)(((size_t)V * H) / 4));
  gemm_lse_kernel<<<nmb * nvb, 256, 0, stream>>>(xb, wb, pm, ps, N, H, V);
  reduce_kernel<<<N / 4, 256, 0, stream>>>(pm, ps, xb, wb, tgt, accum, N, H, nvb);
  finalize_kernel<<<1, 1, 0, stream>>>(accum, out);
}

// Round 3
// 3148.624 us; speedup vs baseline: 1.1478x; 1.1478x over previous
//
#include <hip/hip_runtime.h>
#include <hip/hip_bf16.h>
#include <stdint.h>

typedef __attribute__((ext_vector_type(8))) __bf16 bf16x8;
typedef __attribute__((ext_vector_type(8))) unsigned short us8;
typedef __attribute__((ext_vector_type(4))) float f32x4;

#define BM 256
#define BN 256
#define BK 64
#define NT_TILES 64   // H / BK

__device__ inline float bf2f(unsigned short u) {
  unsigned v = ((unsigned)u) << 16;
  float f;
  __builtin_memcpy(&f, &v, 4);
  return f;
}

__device__ inline unsigned short f2bf(float f) {
  unsigned u;
  __builtin_memcpy(&u, &f, 4);
  u += 0x7FFFu + ((u >> 16) & 1u);  // RNE
  return (unsigned short)(u >> 16);
}

__device__ inline void gload16(const void* g, void* l) {
  __builtin_amdgcn_global_load_lds(
      (const __attribute__((address_space(1))) unsigned int*)g,
      (__attribute__((address_space(3))) unsigned int*)l, 16, 0, 0);
}

// ---------------- fp32 -> bf16 convert ----------------
__global__ void cvt_kernel(const float* __restrict__ in,
                           unsigned short* __restrict__ out, int n4) {
  int i = blockIdx.x * blockDim.x + threadIdx.x;
  int stride = gridDim.x * blockDim.x;
  const float4* in4 = reinterpret_cast<const float4*>(in);
  ushort4* out4 = reinterpret_cast<ushort4*>(out);
  for (int idx = i; idx < n4; idx += stride) {
    float4 v = in4[idx];
    ushort4 o;
    o.x = f2bf(v.x); o.y = f2bf(v.y); o.z = f2bf(v.z); o.w = f2bf(v.w);
    out4[idx] = o;
  }
}

// ---------------- 256x256 8-phase GEMM + per-tile (max, sumexp) ----------------
// LDS byte layout: buffer b at b*65536; A region +0 (32KB), B region +32768.
// A tile stored [256 rows][128 bytes]; byte (r*128 + c2) holds element
// (r, (c2 ^ ((r&7)<<4))>>1) -- XOR swizzle (T2), applied on the global SOURCE
// during global_load_lds staging (rule 21) and on ds_read addresses.
__launch_bounds__(512, 2)
__global__ void gemm_lse_kernel(const unsigned short* __restrict__ xb,
                                const unsigned short* __restrict__ wb,
                                float* __restrict__ pm, float* __restrict__ ps,
                                int N, int H, int V) {
  __shared__ __align__(16) unsigned char lds[131072];

  const int tid = threadIdx.x;
  const int l = tid & 63;
  const int w = tid >> 6;   // 0..7
  const int wm = w >> 2;    // 0..1 (M half)
  const int wn = w & 3;     // 0..3 (N quarter)

  // T1: bijective XCD swizzle (grid 4000 = 8 * 500)
  const int nwg = gridDim.x;
  const int chunk = nwg >> 3;
  const int sid = (blockIdx.x & 7) * chunk + (blockIdx.x >> 3);
  const int nmb = N / BM;
  const int mb = sid % nmb;
  const int vb = sid / nmb;
  const int brow = mb * BM, bcol = vb * BN;

  // ---- staging addresses (pre-swizzled global source) ----
  const int r8 = tid >> 3;                                  // 0..63
  const int c2src = ((tid & 7) << 4) ^ ((r8 & 7) << 4);     // byte col, 16B aligned
  const unsigned short* srcA = xb + (size_t)(brow + r8) * H + (c2src >> 1);
  const unsigned short* srcB = wb + (size_t)(bcol + r8) * H + (c2src >> 1);
  const int wofs = (tid & 448) << 4;                        // wave*1024 (uniform per wave)

#define STAGE_A(buf, h, g, kt)                                          \
  gload16(srcA + (size_t)((h) * 128 + (g) * 64) * H + (kt),             \
          lds + (buf) * 65536 + (h) * 16384 + (g) * 8192 + wofs)
#define STAGE_B(buf, h, g, kt)                                          \
  gload16(srcB + (size_t)((h) * 128 + (g) * 64) * H + (kt),             \
          lds + (buf) * 65536 + 32768 + (h) * 16384 + (g) * 8192 + wofs)

  // ---- fragment read addresses (swizzled) ----
  const int rA = (wm * 128 + (l & 15)) * 128;   // byte row offset, A region
  const int rB = (wn * 64 + (l & 15)) * 128;    // byte row offset, B region
  const int col0 = (((l >> 4) * 16)) ^ ((l & 7) << 4);  // ks=0
  const int col1 = col0 ^ 64;                           // ks=1

  f32x4 acc[8][4];
#pragma unroll
  for (int mi = 0; mi < 8; ++mi)
#pragma unroll
    for (int ni = 0; ni < 4; ++ni) acc[mi][ni] = (f32x4){0.f, 0.f, 0.f, 0.f};

  bf16x8 afr[4][2];  // current M-half quad x ks
  bf16x8 bfr[4][2];  // all 4 N frags x ks (persist per tile)

  // ---- prologue: stage tile 0 into buf0, full drain once ----
  STAGE_A(0, 0, 0, 0); STAGE_A(0, 0, 1, 0); STAGE_A(0, 1, 0, 0); STAGE_A(0, 1, 1, 0);
  STAGE_B(0, 0, 0, 0); STAGE_B(0, 0, 1, 0); STAGE_B(0, 1, 0, 0); STAGE_B(0, 1, 1, 0);
  asm volatile("s_waitcnt vmcnt(0)" ::: "memory");
  __builtin_amdgcn_s_barrier();

#pragma unroll 2
  for (int t = 0; t < NT_TILES; ++t) {
    const int cur = t & 1;
    const int nxt = cur ^ 1;
    const int ktn = (t + 1) * BK;
    const bool pre = (t + 1 < NT_TILES);
    char* pa = (char*)lds + cur * 65536;
    char* pb = pa + 32768;

    // ======== phase 0: quadrant (mh=0, nh=0); stage A0,B0 of t+1 ========
#pragma unroll
    for (int q = 0; q < 4; ++q) {
      afr[q][0] = *(const bf16x8*)(pa + rA + q * 2048 + col0);
      afr[q][1] = *(const bf16x8*)(pa + rA + q * 2048 + col1);
    }
#pragma unroll
    for (int n = 0; n < 2; ++n) {
      bfr[n][0] = *(const bf16x8*)(pb + rB + n * 2048 + col0);
      bfr[n][1] = *(const bf16x8*)(pb + rB + n * 2048 + col1);
    }
    if (pre) {
      STAGE_A(nxt, 0, 0, ktn); STAGE_A(nxt, 0, 1, ktn);
      STAGE_B(nxt, 0, 0, ktn); STAGE_B(nxt, 0, 1, ktn);
    }
    __builtin_amdgcn_s_barrier();
    asm volatile("s_waitcnt lgkmcnt(0)" ::: "memory");
    __builtin_amdgcn_sched_barrier(0);
    __builtin_amdgcn_s_setprio(1);
#pragma unroll
    for (int q = 0; q < 4; ++q)
#pragma unroll
      for (int n = 0; n < 2; ++n) {
        acc[q][n] = __builtin_amdgcn_mfma_f32_16x16x32_bf16(afr[q][0], bfr[n][0], acc[q][n], 0, 0, 0);
        acc[q][n] = __builtin_amdgcn_mfma_f32_16x16x32_bf16(afr[q][1], bfr[n][1], acc[q][n], 0, 0, 0);
      }
    __builtin_amdgcn_s_setprio(0);
    __builtin_amdgcn_s_barrier();

    // ======== phase 1: quadrant (mh=0, nh=1); stage A1,B1 of t+1 ========
#pragma unroll
    for (int n = 0; n < 2; ++n) {
      bfr[2 + n][0] = *(const bf16x8*)(pb + rB + (2 + n) * 2048 + col0);
      bfr[2 + n][1] = *(const bf16x8*)(pb + rB + (2 + n) * 2048 + col1);
    }
    if (pre) {
      STAGE_A(nxt, 1, 0, ktn); STAGE_A(nxt, 1, 1, ktn);
      STAGE_B(nxt, 1, 0, ktn); STAGE_B(nxt, 1, 1, ktn);
    }
    __builtin_amdgcn_s_barrier();
    asm volatile("s_waitcnt lgkmcnt(0)" ::: "memory");
    __builtin_amdgcn_sched_barrier(0);
    __builtin_amdgcn_s_setprio(1);
#pragma unroll
    for (int q = 0; q < 4; ++q)
#pragma unroll
      for (int n = 0; n < 2; ++n) {
        acc[q][2 + n] = __builtin_amdgcn_mfma_f32_16x16x32_bf16(afr[q][0], bfr[2 + n][0], acc[q][2 + n], 0, 0, 0);
        acc[q][2 + n] = __builtin_amdgcn_mfma_f32_16x16x32_bf16(afr[q][1], bfr[2 + n][1], acc[q][2 + n], 0, 0, 0);
      }
    __builtin_amdgcn_s_setprio(0);
    __builtin_amdgcn_s_barrier();

    // ======== phase 2: quadrant (mh=1, nh=1); reload afr ========
#pragma unroll
    for (int q = 0; q < 4; ++q) {
      afr[q][0] = *(const bf16x8*)(pa + rA + (4 + q) * 2048 + col0);
      afr[q][1] = *(const bf16x8*)(pa + rA + (4 + q) * 2048 + col1);
    }
    __builtin_amdgcn_s_barrier();
    asm volatile("s_waitcnt lgkmcnt(0)" ::: "memory");
    __builtin_amdgcn_sched_barrier(0);
    __builtin_amdgcn_s_setprio(1);
#pragma unroll
    for (int q = 0; q < 4; ++q)
#pragma unroll
      for (int n = 0; n < 2; ++n) {
        acc[4 + q][2 + n] = __builtin_amdgcn_mfma_f32_16x16x32_bf16(afr[q][0], bfr[2 + n][0], acc[4 + q][2 + n], 0, 0, 0);
        acc[4 + q][2 + n] = __builtin_amdgcn_mfma_f32_16x16x32_bf16(afr[q][1], bfr[2 + n][1], acc[4 + q][2 + n], 0, 0, 0);
      }
    __builtin_amdgcn_s_setprio(0);
    __builtin_amdgcn_s_barrier();

    // ======== phase 3: quadrant (mh=1, nh=0); aged drain of t+1 loads ========
    asm volatile("s_waitcnt vmcnt(0)" ::: "memory");  // newest issue is 2 phases old
    __builtin_amdgcn_s_barrier();
    __builtin_amdgcn_sched_barrier(0);
    __builtin_amdgcn_s_setprio(1);
#pragma unroll
    for (int q = 0; q < 4; ++q)
#pragma unroll
      for (int n = 0; n < 2; ++n) {
        acc[4 + q][n] = __builtin_amdgcn_mfma_f32_16x16x32_bf16(afr[q][0], bfr[n][0], acc[4 + q][n], 0, 0, 0);
        acc[4 + q][n] = __builtin_amdgcn_mfma_f32_16x16x32_bf16(afr[q][1], bfr[n][1], acc[4 + q][n], 0, 0, 0);
      }
    __builtin_amdgcn_s_setprio(0);
    __builtin_amdgcn_s_barrier();
  }
#undef STAGE_A
#undef STAGE_B

  // ---- epilogue: per-row (max, sumexp) over this tile's 256 columns ----
  // C frag layout: col = wn*64 + ni*16 + (lane&15), row = wm*128 + mi*16 + (lane>>4)*4 + j
  __syncthreads();
  float* redm = (float*)(void*)lds;            // [4][256]
  float* reds = (float*)(void*)(lds + 4096);   // [4][256]

#pragma unroll
  for (int mi = 0; mi < 8; ++mi) {
#pragma unroll
    for (int j = 0; j < 4; ++j) {
      float m = acc[mi][0][j];
#pragma unroll
      for (int n = 1; n < 4; ++n) m = fmaxf(m, acc[mi][n][j]);
#pragma unroll
      for (int off = 1; off < 16; off <<= 1) m = fmaxf(m, __shfl_xor(m, off, 64));
      float s = 0.f;
#pragma unroll
      for (int n = 0; n < 4; ++n) s += __expf(acc[mi][n][j] - m);
#pragma unroll
      for (int off = 1; off < 16; off <<= 1) s += __shfl_xor(s, off, 64);
      if ((l & 15) == 0) {
        const int row = wm * 128 + mi * 16 + (l >> 4) * 4 + j;
        redm[wn * 256 + row] = m;
        reds[wn * 256 + row] = s;
      }
    }
  }
  __syncthreads();
  if (tid < 256) {
    const int row = tid;
    float M = redm[row];
    M = fmaxf(M, redm[256 + row]);
    M = fmaxf(M, redm[512 + row]);
    M = fmaxf(M, redm[768 + row]);
    float S = 0.f;
#pragma unroll
    for (int k = 0; k < 4; ++k)
      S += reds[k * 256 + row] * __expf(redm[k * 256 + row] - M);
    const size_t o = (size_t)vb * N + brow + row;
    pm[o] = M;
    ps[o] = S;
  }
}

// ---------------- per-row LSE merge + target logit + loss accumulate ----------------
__global__ void reduce_kernel(const float* __restrict__ pm,
                              const float* __restrict__ ps,
                              const unsigned short* __restrict__ xb,
                              const unsigned short* __restrict__ wb,
                              const int* __restrict__ tgt,
                              float* __restrict__ accum,  // [0]=sum nll, [1]=count
                              int N, int H, int nvb) {
  const int l = threadIdx.x & 63;
  const int w = threadIdx.x >> 6;
  const int row = blockIdx.x * 4 + w;
  if (row >= N) return;

  float M = -INFINITY, S = 0.f;
  for (int vb = l; vb < nvb; vb += 64) {
    const float m = pm[(size_t)vb * N + row];
    const float s = ps[(size_t)vb * N + row];
    const float nM = fmaxf(M, m);
    S = S * __expf(M - nM) + s * __expf(m - nM);
    M = nM;
  }
#pragma unroll
  for (int off = 1; off < 64; off <<= 1) {
    const float om = __shfl_xor(M, off, 64);
    const float os = __shfl_xor(S, off, 64);
    const float nM = fmaxf(M, om);
    S = S * __expf(M - nM) + os * __expf(om - nM);
    M = nM;
  }

  const int t = tgt[row];
  const bool valid = (t != -100);
  float dot = 0.f;
  if (valid) {
    const unsigned short* xr = xb + (size_t)row * H;
    const unsigned short* wrow = wb + (size_t)t * H;
    for (int k = l * 8; k < H; k += 64 * 8) {
      const us8 xv = *reinterpret_cast<const us8*>(xr + k);
      const us8 wv = *reinterpret_cast<const us8*>(wrow + k);
#pragma unroll
      for (int j = 0; j < 8; ++j) dot += bf2f(xv[j]) * bf2f(wv[j]);
    }
#pragma unroll
    for (int off = 1; off < 64; off <<= 1) dot += __shfl_xor(dot, off, 64);
  }

  if (l == 0) {
    const float lse = M + __logf(S);
    const float nll = valid ? (lse - dot) : 0.f;
    atomicAdd(&accum[0], nll);
    if (valid) atomicAdd(&accum[1], 1.f);
  }
}

__global__ void finalize_kernel(const float* __restrict__ accum,
                                float* __restrict__ out) {
  out[0] = accum[0] / fmaxf(accum[1], 1.f);
}

extern "C" void kernel_launch(void* const* d_in, const int* in_sizes, int n_in,
                              void* d_out, int out_size, void* d_ws,
                              size_t ws_size, hipStream_t stream) {
  const float* x = (const float*)d_in[0];
  const float* wt = (const float*)d_in[1];
  const int* tgt = (const int*)d_in[2];
  float* out = (float*)d_out;

  const int N = in_sizes[2];            // 8192
  const int H = in_sizes[0] / N;        // 4096
  const int V = in_sizes[1] / H;        // 32000
  const int nvb = V / BN;               // 125
  const int nmb = N / BM;               // 32

  unsigned char* ws = (unsigned char*)d_ws;
  unsigned short* xb = (unsigned short*)ws;
  size_t off = (size_t)N * H * 2;
  unsigned short* wb = (unsigned short*)(ws + off);
  off += (size_t)V * H * 2;
  float* pm = (float*)(ws + off);
  off += (size_t)nvb * N * 4;
  float* ps = (float*)(ws + off);
  off += (size_t)nvb * N * 4;
  float* accum = (float*)(ws + off);

  hipMemsetAsync(accum, 0, 2 * sizeof(float), stream);

  cvt_kernel<<<2048, 256, 0, stream>>>(x, xb, (int)(((size_t)N * H) / 4));
  cvt_kernel<<<4096, 256, 0, stream>>>(wt, wb, (int)(((size_t)V * H) / 4));
  gemm_lse_kernel<<<nmb * nvb, 512, 0, stream>>>(xb, wb, pm, ps, N, H, V);
  reduce_kernel<<<N / 4, 256, 0, stream>>>(pm, ps, xb, wb, tgt, accum, N, H, nvb);
  finalize_kernel<<<1, 1, 0, stream>>>(accum, out);
}